// Round 16
// baseline (56.005 us; speedup 1.0000x reference)
//
#include <hip/hip_runtime.h>
#include <hip/hip_bf16.h>
#include <stdint.h>

typedef short bf16x8 __attribute__((ext_vector_type(8)));
typedef short bf16x4 __attribute__((ext_vector_type(4)));
typedef float f32x4 __attribute__((ext_vector_type(4)));

#define NN 4096

static __device__ __forceinline__ short f2b(float f) {
    union { float f; uint32_t u; } a; a.f = f;
    uint32_t r = a.u + 0x7FFFu + ((a.u >> 16) & 1u);
    return (short)(r >> 16);
}

// ---- output region offsets (in floats) ----
#define OFF_QMV   0UL
#define OFF_KMV   8388608UL
#define OFF_VMV   16777216UL
#define OFF_VMVQ  25165824UL
#define OFF_QS    33554432UL
#define OFF_KS    35651584UL
#define OFF_VS    37748736UL
#define OFF_VSQ   39845888UL

// ---- ws layout (bf16 elements) ----
#define WS_BMV_END   73728
#define WS_SW_BASE   106496
#define WS_PACK_END  270336    // shorts -> 540,672 bytes of scratch

static __device__ __forceinline__ int mv_chan(int ct, int l) {
    return (ct >> 2) * 64 + (l & 7) * 8 + (ct & 3) * 2 + ((l >> 3) & 1);
}
static __device__ __forceinline__ int s_chan(int ct, int lr) {
    int hid = (ct & 3) + 4 * (lr >> 3) + 8 * (ct >> 2);
    return (lr & 7) + 8 * hid;
}

// ============ prep: weight fragment packs only ==============================
__global__ __launch_bounds__(256) void prep_pack(
    const float* __restrict__ qwmv,   const float* __restrict__ qws2mv,
    const float* __restrict__ qwmv2s, const float* __restrict__ qws2s,
    const float* __restrict__ kvwmv,  const float* __restrict__ kvws2mv,
    const float* __restrict__ kvwmv2s,const float* __restrict__ kvws2s,
    short* __restrict__ ws)
{
    const int id = blockIdx.x * 256 + threadIdx.x;
    if (id >= WS_PACK_END) return;
    float v;
    if (id < WS_BMV_END) {
        int rem = id; int task = rem / 36864; rem -= task * 36864;
        int y = rem / 4096; rem -= y * 4096;
        int ct = rem >> 9; int l = (rem >> 3) & 63; int e = rem & 7;
        int o = mv_chan(ct, l);
        int i = (l >> 4) * 8 + e;
        const float* w = (task == 0 || o >= 64) ? kvwmv : qwmv;
        v = w[(o * 32 + i) * 9 + y];
    } else if (id < WS_SW_BASE) {
        int rem = id - WS_BMV_END; int task = rem / 16384; rem -= task * 16384;
        int kk = rem / 4096; rem -= kk * 4096;
        int ct = rem >> 9; int l = (rem >> 3) & 63; int e = rem & 7;
        int o = mv_chan(ct, l);
        int k = kk * 32 + (l >> 4) * 8 + e;
        const float* w = (task == 0 || o >= 64) ? kvws2mv : qws2mv;
        v = w[o * 128 + k];
    } else {
        int rem = id - WS_SW_BASE; int task = rem / 81920; rem -= task * 81920;
        int ct = rem / 2560; rem -= ct * 2560;
        int lr = rem / 160;  int k = rem - lr * 160;
        int o = s_chan(ct, lr);
        if (k < 32) {
            const float* w = (task == 0 || o >= 256) ? kvwmv2s : qwmv2s;
            v = w[o * 32 + k];
        } else {
            const float* w = (task == 0 || o >= 256) ? kvws2s : qws2s;
            v = w[o * 128 + (k - 32)];
        }
    }
    ws[id] = f2b(v);
}

// ==== fused, 2048 half-work blocks: twin h splits ct-work for generational
// mixing (grid > resident capacity -> later blocks' reads overlap earlier
// blocks' store drains, approximating r14's measured 35.5us/rep steady state).
__global__ __launch_bounds__(128) void fused_all(
    const float* __restrict__ inputs, const float* __restrict__ scalars,
    const float* __restrict__ q_b_s,  const float* __restrict__ kv_b_s,
    const int* __restrict__ q_idx,    const int* __restrict__ kv_idx,
    const short* __restrict__ ws,     float* __restrict__ out)
{
    const int GR[16]   = {0,1,1,1,1,2,2,2,2,2,2,3,3,3,3,4};
    const int SRC[16]  = {-1,0,-1,-1,-1,2,3,4,-1,-1,-1,8,9,10,-1,14};
    const int EMAP[16] = {0,5,0,0,0,6,6,6,0,0,0,7,7,7,0,8};

    __shared__ __align__(16) char SMEM[32768];
    short* XA = (short*)SMEM;            // [r:16][x:16][i:32], row stride 520
    short* XS = XA + 16 * 520;           // [r:16][k:128], stride 136

    const int tid  = threadIdx.x;
    const int h    = blockIdx.x & 1;     // work-half (twin blocks adjacent)
    const int bid  = blockIdx.x >> 1;
    const int tile = bid & 255;
    const int b    = (bid >> 8) & 1;
    const int task = bid >> 9;          // 0 = kv-task, 1 = q-task
    const int n0   = tile * 16;
    const int* ridx = task ? q_idx : kv_idx;

    // ---- staging: gather fp32 rows, convert in registers, write LDS ----
    {
        const int r = tid >> 3, c = tid & 7;    // 8 threads per row
        const int m = ridx[n0 + r];
        const float* arow = inputs + (size_t)(b * NN + m) * 512;
        short t4[4][16];
        #pragma unroll
        for (int ii = 0; ii < 4; ++ii)
            #pragma unroll
            for (int q = 0; q < 4; ++q) {
                const float4 v = *(const float4*)(arow + (4 * c + ii) * 16 + q * 4);
                t4[ii][q * 4 + 0] = f2b(v.x); t4[ii][q * 4 + 1] = f2b(v.y);
                t4[ii][q * 4 + 2] = f2b(v.z); t4[ii][q * 4 + 3] = f2b(v.w);
            }
        #pragma unroll
        for (int x = 0; x < 16; ++x) {
            bf16x4 pr = {t4[0][x], t4[1][x], t4[2][x], t4[3][x]};
            *(bf16x4*)(XA + r * 520 + x * 32 + 4 * c) = pr;   // b64
        }
        const float* srow = scalars + (size_t)(b * NN + m) * 128 + c * 16;
        #pragma unroll
        for (int hh = 0; hh < 2; ++hh) {
            const float4 s0 = *(const float4*)(srow + hh * 8);
            const float4 s1 = *(const float4*)(srow + hh * 8 + 4);
            bf16x8 sv = {f2b(s0.x), f2b(s0.y), f2b(s0.z), f2b(s0.w),
                         f2b(s1.x), f2b(s1.y), f2b(s1.z), f2b(s1.w)};
            *(bf16x8*)(XS + r * 136 + c * 16 + hh * 8) = sv;
        }
    }
    __syncthreads();

    const int w  = tid >> 6;    // 2 waves
    const int l  = tid & 63;
    const int lr = l & 15;
    const int lg = l >> 4;

    // ---- hoist all A fragments to registers (read LDS once) ----
    bf16x8 Ax[16];
    #pragma unroll
    for (int x = 0; x < 16; ++x)
        Ax[x] = *(const bf16x8*)(XA + lr * 520 + x * 32 + lg * 8);
    bf16x8 Sx[4];
    #pragma unroll
    for (int kk = 0; kk < 4; ++kk)
        Sx[kk] = *(const bf16x8*)(XS + lr * 136 + kk * 32 + lg * 8);
    __syncthreads();   // XA/XS dead; SMEM becomes per-wave OUT buffers

    float* OUTw = (float*)SMEM + w * 4096;   // [row:32][128 floats], 16 KB/wave

    // ====== MV phase: wave w, half h -> cts {4w+2h, 4w+2h+1} ======
    #pragma unroll
    for (int cc2 = 0; cc2 < 2; ++cc2) {
        const int ct = 4 * w + 2 * h + cc2;
        bf16x8 Bg[9];
        #pragma unroll
        for (int y = 0; y < 9; ++y)
            Bg[y] = *(const bf16x8*)(ws + ((((size_t)task * 9 + y) * 8 + ct) * 64 + l) * 8);

        #pragma unroll
        for (int xc = 0; xc < 4; ++xc) {
            f32x4 acc[4];
            #pragma unroll
            for (int q = 0; q < 4; ++q) {
                const int x = xc * 4 + q;
                f32x4 a0 = {0.f, 0.f, 0.f, 0.f};
                a0 = __builtin_amdgcn_mfma_f32_16x16x32_bf16(Ax[x], Bg[GR[x]], a0, 0, 0, 0);
                if (SRC[x] >= 0)
                    a0 = __builtin_amdgcn_mfma_f32_16x16x32_bf16(Ax[SRC[x]], Bg[EMAP[x]], a0, 0, 0, 0);
                if (x == 0) {
                    #pragma unroll
                    for (int kk = 0; kk < 4; ++kk) {
                        bf16x8 bs2 = *(const bf16x8*)(ws + WS_BMV_END +
                                       ((((size_t)task * 4 + kk) * 8 + ct) * 64 + l) * 8);
                        a0 = __builtin_amdgcn_mfma_f32_16x16x32_bf16(Sx[kk], bs2, a0, 0, 0, 0);
                    }
                }
                acc[q] = a0;
            }
            #pragma unroll
            for (int j = 0; j < 4; ++j) {
                const int roww = (lr >> 3) * 16 + lg * 4 + j;
                const int cqw  = ((lr & 7) * 4 + xc) ^ ((roww >> 2) & 7);
                *(f32x4*)(OUTw + roww * 128 + cqw * 4) =
                    (f32x4){acc[0][j], acc[1][j], acc[2][j], acc[3][j]};
            }
        }

        // readback + coalesced store: 1 KB contiguous per instr
        const int region = ct >> 2;
        const size_t obase = task ? (region ? OFF_VMVQ : OFF_QMV)
                                  : (region ? OFF_VMV  : OFF_KMV);
        #pragma unroll
        for (int t = 0; t < 16; ++t) {
            const int row  = 2 * t + (l >> 5);
            const int h2   = row >> 4, nl = row & 15;
            const int head = (ct & 3) * 2 + h2;
            const int cq   = (l & 31) ^ ((row >> 2) & 7);
            f32x4 v = *(const f32x4*)(OUTw + row * 128 + cq * 4);
            *(f32x4*)(out + obase + (((size_t)(b * 8 + head)) * NN + n0 + nl) * 128
                      + (l & 31) * 4) = v;
        }
    }

    // ====== S phase: wave w, half h -> q8 in {2h, 2h+1} ======
    float* OUTS = (float*)SMEM;            // [R:256][32 floats], wave-split

    #pragma unroll
    for (int q8i = 0; q8i < 2; ++q8i) {
        const int q8 = 2 * h + q8i;
        const int hidbase = 32 * w + 8 * q8 + 4 * (lr >> 3);
        const int head    = lr & 7;
        const int hq      = hidbase >> 2;
        f32x4 acc4[4];
        #pragma unroll
        for (int jj = 0; jj < 4; ++jj) {
            const int ct = w * 16 + q8 * 4 + jj;
            const short* bp = ws + WS_SW_BASE +
                              (((size_t)task * 32 + ct) * 16 + lr) * 160 + lg * 8;
            f32x4 acc = {0.f, 0.f, 0.f, 0.f};
            acc = __builtin_amdgcn_mfma_f32_16x16x32_bf16(Ax[0], *(const bf16x8*)bp, acc, 0, 0, 0);
            #pragma unroll
            for (int c = 0; c < 4; ++c)
                acc = __builtin_amdgcn_mfma_f32_16x16x32_bf16(
                          Sx[c], *(const bf16x8*)(bp + 32 + c * 32), acc, 0, 0, 0);
            acc4[jj] = acc;
        }
        float bs[4];
        #pragma unroll
        for (int jj = 0; jj < 4; ++jj) {
            const int o = head + 8 * (hidbase + jj);
            bs[jj] = (task == 0) ? kv_b_s[o] : ((o < 256) ? q_b_s[o] : kv_b_s[o]);
        }
        const int c = (hq & 7) ^ head;
        #pragma unroll
        for (int j = 0; j < 4; ++j) {
            const int R = w * 128 + head * 16 + lg * 4 + j;
            *(f32x4*)(OUTS + R * 32 + c * 4) =
                (f32x4){acc4[0][j] + bs[0], acc4[1][j] + bs[1],
                        acc4[2][j] + bs[2], acc4[3][j] + bs[3]};
        }
    }

    // readback + store: this half wrote quads [4h,4h+4) of each row.
    // Per instr: 16 clusters x 64B full aligned lines (no partial lines).
    {
        const size_t obase = task ? (w ? OFF_VSQ : OFF_QS)
                                  : (w ? OFF_VS  : OFF_KS);
        const int cl   = l >> 2;          // 16 clusters
        const int li   = l & 3;
        const int head = cl & 7;
        const int hq   = 4 * h + li;      // quad within region half
        const int c    = hq ^ head;       // dump-side swizzle inverse
        #pragma unroll
        for (int j = 0; j < 8; ++j) {
            const int nl = j * 2 + (cl >> 3);
            f32x4 v = *(const f32x4*)(OUTS + ((w * 128 + head * 16 + nl)) * 32 + c * 4);
            *(f32x4*)(out + obase + (((size_t)(b * 8 + head)) * NN + n0 + nl) * 32
                      + hq * 4) = v;
        }
    }
}

extern "C" void kernel_launch(void* const* d_in, const int* in_sizes, int n_in,
                              void* d_out, int out_size, void* d_ws, size_t ws_size,
                              hipStream_t stream) {
    const float* inputs  = (const float*)d_in[0];
    const float* scalars = (const float*)d_in[1];
    const float* qwmv    = (const float*)d_in[2];
    const float* qws2mv  = (const float*)d_in[3];
    const float* qwmv2s  = (const float*)d_in[4];
    const float* qws2s   = (const float*)d_in[5];
    const float* qbs     = (const float*)d_in[6];
    const float* kvwmv   = (const float*)d_in[7];
    const float* kvws2mv = (const float*)d_in[8];
    const float* kvwmv2s = (const float*)d_in[9];
    const float* kvws2s  = (const float*)d_in[10];
    const float* kvbs    = (const float*)d_in[11];
    const int*   qidx    = (const int*)d_in[12];
    const int*   kvidx   = (const int*)d_in[13];
    short* ws   = (short*)d_ws;            // 540,672 B of scratch used
    float* outp = (float*)d_out;

    prep_pack<<<(WS_PACK_END + 255) / 256, 256, 0, stream>>>(
        qwmv, qws2mv, qwmv2s, qws2s, kvwmv, kvws2mv, kvwmv2s, kvws2s, ws);

    fused_all<<<2048, 128, 0, stream>>>(
        inputs, scalars, qbs, kvbs, qidx, kvidx, ws, outp);
}

// Round 17
// 46.741 us; speedup vs baseline: 1.1982x; 1.1982x over previous
//
#include <hip/hip_runtime.h>
#include <hip/hip_bf16.h>
#include <stdint.h>

typedef short bf16x8 __attribute__((ext_vector_type(8)));
typedef short bf16x4 __attribute__((ext_vector_type(4)));
typedef float f32x4 __attribute__((ext_vector_type(4)));

#define NN 4096

static __device__ __forceinline__ short f2b(float f) {
    union { float f; uint32_t u; } a; a.f = f;
    uint32_t r = a.u + 0x7FFFu + ((a.u >> 16) & 1u);
    return (short)(r >> 16);
}

// ---- output region offsets (in floats) ----
#define OFF_QMV   0UL
#define OFF_KMV   8388608UL
#define OFF_VMV   16777216UL
#define OFF_VMVQ  25165824UL
#define OFF_QS    33554432UL
#define OFF_KS    35651584UL
#define OFF_VS    37748736UL
#define OFF_VSQ   39845888UL

// ---- ws layout (bf16 elements) ----
#define WS_BMV_END   73728
#define WS_SW_BASE   106496
#define WS_PACK_END  270336    // shorts -> 540,672 bytes of scratch

static __device__ __forceinline__ int mv_chan(int ct, int l) {
    return (ct >> 2) * 64 + (l & 7) * 8 + (ct & 3) * 2 + ((l >> 3) & 1);
}
static __device__ __forceinline__ int s_chan(int ct, int lr) {
    int hid = (ct & 3) + 4 * (lr >> 3) + 8 * (ct >> 2);
    return (lr & 7) + 8 * hid;
}

// ============ prep: weight fragment packs only ==============================
__global__ __launch_bounds__(256) void prep_pack(
    const float* __restrict__ qwmv,   const float* __restrict__ qws2mv,
    const float* __restrict__ qwmv2s, const float* __restrict__ qws2s,
    const float* __restrict__ kvwmv,  const float* __restrict__ kvws2mv,
    const float* __restrict__ kvwmv2s,const float* __restrict__ kvws2s,
    short* __restrict__ ws)
{
    const int id = blockIdx.x * 256 + threadIdx.x;
    if (id >= WS_PACK_END) return;
    float v;
    if (id < WS_BMV_END) {
        int rem = id; int task = rem / 36864; rem -= task * 36864;
        int y = rem / 4096; rem -= y * 4096;
        int ct = rem >> 9; int l = (rem >> 3) & 63; int e = rem & 7;
        int o = mv_chan(ct, l);
        int i = (l >> 4) * 8 + e;
        const float* w = (task == 0 || o >= 64) ? kvwmv : qwmv;
        v = w[(o * 32 + i) * 9 + y];
    } else if (id < WS_SW_BASE) {
        int rem = id - WS_BMV_END; int task = rem / 16384; rem -= task * 16384;
        int kk = rem / 4096; rem -= kk * 4096;
        int ct = rem >> 9; int l = (rem >> 3) & 63; int e = rem & 7;
        int o = mv_chan(ct, l);
        int k = kk * 32 + (l >> 4) * 8 + e;
        const float* w = (task == 0 || o >= 64) ? kvws2mv : qws2mv;
        v = w[o * 128 + k];
    } else {
        int rem = id - WS_SW_BASE; int task = rem / 81920; rem -= task * 81920;
        int ct = rem / 2560; rem -= ct * 2560;
        int lr = rem / 160;  int k = rem - lr * 160;
        int o = s_chan(ct, lr);
        if (k < 32) {
            const float* w = (task == 0 || o >= 256) ? kvwmv2s : qwmv2s;
            v = w[o * 32 + k];
        } else {
            const float* w = (task == 0 || o >= 256) ? kvws2s : qws2s;
            v = w[o * 128 + (k - 32)];
        }
    }
    ws[id] = f2b(v);
}

// ==== BEST-MEASURED KERNEL (round 10, 46.5us): 2-wave blocks, in-register
// f2b staging, register-hoisted A-fragments, LDS-transposed 1KB-contiguous
// nontemporal stores, no block-wide sync after fragment hoist. ====
__global__ __launch_bounds__(128) void fused_all(
    const float* __restrict__ inputs, const float* __restrict__ scalars,
    const float* __restrict__ q_b_s,  const float* __restrict__ kv_b_s,
    const int* __restrict__ q_idx,    const int* __restrict__ kv_idx,
    const short* __restrict__ ws,     float* __restrict__ out)
{
    const int GR[16]   = {0,1,1,1,1,2,2,2,2,2,2,3,3,3,3,4};
    const int SRC[16]  = {-1,0,-1,-1,-1,2,3,4,-1,-1,-1,8,9,10,-1,14};
    const int EMAP[16] = {0,5,0,0,0,6,6,6,0,0,0,7,7,7,0,8};

    __shared__ __align__(16) char SMEM[32768];
    short* XA = (short*)SMEM;            // [r:16][x:16][i:32], row stride 520
    short* XS = XA + 16 * 520;           // [r:16][k:128], stride 136

    const int tid  = threadIdx.x;
    const int bid  = blockIdx.x;
    const int tile = bid & 255;
    const int b    = (bid >> 8) & 1;
    const int task = bid >> 9;          // 0 = kv-task, 1 = q-task
    const int n0   = tile * 16;
    const int* ridx = task ? q_idx : kv_idx;

    // ---- staging: gather fp32 rows, convert in registers, write LDS ----
    {
        const int r = tid >> 3, c = tid & 7;    // 8 threads per row
        const int m = ridx[n0 + r];
        const float* arow = inputs + (size_t)(b * NN + m) * 512;
        short t4[4][16];
        #pragma unroll
        for (int ii = 0; ii < 4; ++ii)
            #pragma unroll
            for (int q = 0; q < 4; ++q) {
                const float4 v = *(const float4*)(arow + (4 * c + ii) * 16 + q * 4);
                t4[ii][q * 4 + 0] = f2b(v.x); t4[ii][q * 4 + 1] = f2b(v.y);
                t4[ii][q * 4 + 2] = f2b(v.z); t4[ii][q * 4 + 3] = f2b(v.w);
            }
        #pragma unroll
        for (int x = 0; x < 16; ++x) {
            bf16x4 pr = {t4[0][x], t4[1][x], t4[2][x], t4[3][x]};
            *(bf16x4*)(XA + r * 520 + x * 32 + 4 * c) = pr;   // b64
        }
        const float* srow = scalars + (size_t)(b * NN + m) * 128 + c * 16;
        #pragma unroll
        for (int h = 0; h < 2; ++h) {
            const float4 s0 = *(const float4*)(srow + h * 8);
            const float4 s1 = *(const float4*)(srow + h * 8 + 4);
            bf16x8 sv = {f2b(s0.x), f2b(s0.y), f2b(s0.z), f2b(s0.w),
                         f2b(s1.x), f2b(s1.y), f2b(s1.z), f2b(s1.w)};
            *(bf16x8*)(XS + r * 136 + c * 16 + h * 8) = sv;
        }
    }
    __syncthreads();

    const int w  = tid >> 6;    // 2 waves
    const int l  = tid & 63;
    const int lr = l & 15;
    const int lg = l >> 4;

    // ---- hoist all A fragments to registers (read LDS once) ----
    bf16x8 Ax[16];
    #pragma unroll
    for (int x = 0; x < 16; ++x)
        Ax[x] = *(const bf16x8*)(XA + lr * 520 + x * 32 + lg * 8);
    bf16x8 Sx[4];
    #pragma unroll
    for (int kk = 0; kk < 4; ++kk)
        Sx[kk] = *(const bf16x8*)(XS + lr * 136 + kk * 32 + lg * 8);
    __syncthreads();   // last barrier: XA/XS dead, SMEM becomes per-wave OUT.
    // After this, wave w only touches SMEM bytes [16384*w, 16384*(w+1)).

    float* OUTw = (float*)SMEM + w * 4096;   // [row:32][128 floats], 16 KB/wave

    // ================= MV phase: wave w handles ct in {4w..4w+3} =================
    #pragma unroll
    for (int cc = 0; cc < 4; ++cc) {
        const int ct = 4 * w + cc;
        bf16x8 Bg[9];
        #pragma unroll
        for (int y = 0; y < 9; ++y)
            Bg[y] = *(const bf16x8*)(ws + ((((size_t)task * 9 + y) * 8 + ct) * 64 + l) * 8);

        #pragma unroll
        for (int xc = 0; xc < 4; ++xc) {
            f32x4 acc[4];
            #pragma unroll
            for (int q = 0; q < 4; ++q) {
                const int x = xc * 4 + q;
                f32x4 a0 = {0.f, 0.f, 0.f, 0.f};
                a0 = __builtin_amdgcn_mfma_f32_16x16x32_bf16(Ax[x], Bg[GR[x]], a0, 0, 0, 0);
                if (SRC[x] >= 0)
                    a0 = __builtin_amdgcn_mfma_f32_16x16x32_bf16(Ax[SRC[x]], Bg[EMAP[x]], a0, 0, 0, 0);
                if (x == 0) {
                    #pragma unroll
                    for (int kk = 0; kk < 4; ++kk) {
                        bf16x8 bs2 = *(const bf16x8*)(ws + WS_BMV_END +
                                       ((((size_t)task * 4 + kk) * 8 + ct) * 64 + l) * 8);
                        a0 = __builtin_amdgcn_mfma_f32_16x16x32_bf16(Sx[kk], bs2, a0, 0, 0, 0);
                    }
                }
                acc[q] = a0;
            }
            #pragma unroll
            for (int j = 0; j < 4; ++j) {
                const int roww = (lr >> 3) * 16 + lg * 4 + j;
                const int cqw  = ((lr & 7) * 4 + xc) ^ ((roww >> 2) & 7);
                *(f32x4*)(OUTw + roww * 128 + cqw * 4) =
                    (f32x4){acc[0][j], acc[1][j], acc[2][j], acc[3][j]};
            }
        }

        // readback + coalesced nontemporal store: 1 KB contiguous per instr
        const int region = ct >> 2;
        const size_t obase = task ? (region ? OFF_VMVQ : OFF_QMV)
                                  : (region ? OFF_VMV  : OFF_KMV);
        #pragma unroll
        for (int t = 0; t < 16; ++t) {
            const int row  = 2 * t + (l >> 5);
            const int h2   = row >> 4, nl = row & 15;
            const int head = (ct & 3) * 2 + h2;
            const int cq   = (l & 31) ^ ((row >> 2) & 7);
            f32x4 v = *(const f32x4*)(OUTw + row * 128 + cq * 4);
            __builtin_nontemporal_store(v,
                (f32x4*)(out + obase + (((size_t)(b * 8 + head)) * NN + n0 + nl) * 128
                         + (l & 31) * 4));
        }
    }

    // ===== S phase: wave w handles ct in {16w..16w+15}; LDS transpose =====
    float* OUTS = (float*)SMEM;            // [R:256][32 floats], wave-split

    #pragma unroll
    for (int q8 = 0; q8 < 4; ++q8) {
        const int hidbase = 32 * w + 8 * q8 + 4 * (lr >> 3);
        const int head    = lr & 7;
        const int hq      = hidbase >> 2;
        f32x4 acc4[4];
        #pragma unroll
        for (int jj = 0; jj < 4; ++jj) {
            const int ct = w * 16 + q8 * 4 + jj;
            const short* bp = ws + WS_SW_BASE +
                              (((size_t)task * 32 + ct) * 16 + lr) * 160 + lg * 8;
            f32x4 acc = {0.f, 0.f, 0.f, 0.f};
            acc = __builtin_amdgcn_mfma_f32_16x16x32_bf16(Ax[0], *(const bf16x8*)bp, acc, 0, 0, 0);
            #pragma unroll
            for (int c = 0; c < 4; ++c)
                acc = __builtin_amdgcn_mfma_f32_16x16x32_bf16(
                          Sx[c], *(const bf16x8*)(bp + 32 + c * 32), acc, 0, 0, 0);
            acc4[jj] = acc;
        }
        float bs[4];
        #pragma unroll
        for (int jj = 0; jj < 4; ++jj) {
            const int o = head + 8 * (hidbase + jj);
            bs[jj] = (task == 0) ? kv_b_s[o] : ((o < 256) ? q_b_s[o] : kv_b_s[o]);
        }
        const int c = (hq & 7) ^ head;
        #pragma unroll
        for (int j = 0; j < 4; ++j) {
            const int R = w * 128 + head * 16 + lg * 4 + j;
            *(f32x4*)(OUTS + R * 32 + c * 4) =
                (f32x4){acc4[0][j] + bs[0], acc4[1][j] + bs[1],
                        acc4[2][j] + bs[2], acc4[3][j] + bs[3]};
        }
    }

    {
        const size_t obase = task ? (w ? OFF_VSQ : OFF_QS)
                                  : (w ? OFF_VS  : OFF_KS);
        #pragma unroll
        for (int k = 0; k < 16; ++k) {
            const int head = k & 7;
            const int nl   = (k >> 3) * 8 + (l >> 3);
            const int q    = l & 7;
            f32x4 v = *(const f32x4*)(OUTS + ((w * 128 + head * 16 + nl)) * 32
                                      + ((q ^ head) & 7) * 4);
            __builtin_nontemporal_store(v,
                (f32x4*)(out + obase + (((size_t)(b * 8 + head)) * NN + n0 + nl) * 32
                         + q * 4));
        }
    }
}

extern "C" void kernel_launch(void* const* d_in, const int* in_sizes, int n_in,
                              void* d_out, int out_size, void* d_ws, size_t ws_size,
                              hipStream_t stream) {
    const float* inputs  = (const float*)d_in[0];
    const float* scalars = (const float*)d_in[1];
    const float* qwmv    = (const float*)d_in[2];
    const float* qws2mv  = (const float*)d_in[3];
    const float* qwmv2s  = (const float*)d_in[4];
    const float* qws2s   = (const float*)d_in[5];
    const float* qbs     = (const float*)d_in[6];
    const float* kvwmv   = (const float*)d_in[7];
    const float* kvws2mv = (const float*)d_in[8];
    const float* kvwmv2s = (const float*)d_in[9];
    const float* kvws2s  = (const float*)d_in[10];
    const float* kvbs    = (const float*)d_in[11];
    const int*   qidx    = (const int*)d_in[12];
    const int*   kvidx   = (const int*)d_in[13];
    short* ws   = (short*)d_ws;            // 540,672 B of scratch used
    float* outp = (float*)d_out;

    prep_pack<<<(WS_PACK_END + 255) / 256, 256, 0, stream>>>(
        qwmv, qws2mv, qwmv2s, qws2s, kvwmv, kvws2mv, kvwmv2s, kvws2s, ws);

    fused_all<<<1024, 128, 0, stream>>>(
        inputs, scalars, qbs, kvbs, qidx, kvidx, ws, outp);
}